// Round 1
// 690.405 us; speedup vs baseline: 1.0001x; 1.0001x over previous
//
#include <hip/hip_runtime.h>

// Problem constants: B=64, T=512, N=64, M=64
constexpr int B = 64, T = 512, N = 64, M = 64;
#define DT_F (1.0f / 252.0f)
#define GAMMA_F 0.1f

// Broadcast lane l's value of v to all lanes via v_readlane (SGPR result,
// feeds v_fmac as the scalar operand — no DS traffic, no lgkmcnt stalls).
__device__ __forceinline__ float bcast(float v, int l) {
    return __uint_as_float(__builtin_amdgcn_readlane(__float_as_uint(v), l));
}

// One wave handles 4 consecutive t; block = 4 waves = 16 t.
// Grid = B * T/16 = 2048 blocks (8 per CU).
// Lane owns output column m = lane: sigma rows are read as fully-coalesced
// contiguous 256 B per instruction, zeta as a coalesced row, and there is
// ZERO cross-lane traffic in the hot loop (action[n] comes via readlane).
__global__ __launch_bounds__(256) void wealth_partial_kernel(
        const float* __restrict__ action,  // (B,T,N)
        const float* __restrict__ mu,      // (B,N,T)
        const float* __restrict__ sigma,   // (B,T,N,M)
        const float* __restrict__ zeta,    // (B,T,M)
        float* __restrict__ partial) {     // (B*T/4,) laid out [b][128]
    const int lane = threadIdx.x & 63;
    const int wave = threadIdx.x >> 6;
    const int b  = blockIdx.x >> 5;                          // 32 blocks per b
    const int t0 = ((blockIdx.x & 31) << 4) | (wave << 2);   // wave's first t

    const size_t bt0 = (size_t)b * T + t0;

    // Wealth-dot mu operand: one strided float4 gather covers this wave's
    // 4 t (t0 % 4 == 0, rows are 2 KB-aligned). mu has 4x line reuse across
    // neighboring waves -> keep it cacheable (no nt hint).
    const float4 mu4 = *(const float4*)(mu + ((size_t)b * N + lane) * T + t0);

    float d_acc = 0.f, sq_acc = 0.f;

#pragma unroll
    for (int tt = 0; tt < 4; ++tt) {
        const size_t bti = bt0 + tt;
        const float* __restrict__ act = action + bti * N;
        const float* __restrict__ sg  = sigma  + bti * (size_t)(N * M);

        const float a_lane = act[lane];          // action row (coalesced 256 B)
        const float mu_c = (tt == 0) ? mu4.x : (tt == 1) ? mu4.y
                         : (tt == 2) ? mu4.z : mu4.w;
        d_acc = fmaf(a_lane, mu_c, d_acc);

        // risk[m=lane] = sum_n action[n] * sigma[n][lane]
        // 4 independent accumulator chains so loads pipeline 4-deep past the
        // fma latency; sigma is single-use (512 MB) -> non-temporal.
        float ac0 = 0.f, ac1 = 0.f, ac2 = 0.f, ac3 = 0.f;
#pragma unroll
        for (int n = 0; n < N; n += 4) {
            ac0 = fmaf(bcast(a_lane, n + 0),
                       __builtin_nontemporal_load(sg + (n + 0) * M + lane), ac0);
            ac1 = fmaf(bcast(a_lane, n + 1),
                       __builtin_nontemporal_load(sg + (n + 1) * M + lane), ac1);
            ac2 = fmaf(bcast(a_lane, n + 2),
                       __builtin_nontemporal_load(sg + (n + 2) * M + lane), ac2);
            ac3 = fmaf(bcast(a_lane, n + 3),
                       __builtin_nontemporal_load(sg + (n + 3) * M + lane), ac3);
        }
        const float r = ((ac0 + ac1) + (ac2 + ac3))
                      + __builtin_nontemporal_load(zeta + bti * M + lane);
        sq_acc = fmaf(r, r, sq_acc);
    }

    // Single joint full-wave reduction per 4 t (was: one per t).
#pragma unroll
    for (int off = 1; off < 64; off <<= 1) {
        d_acc  += __shfl_xor(d_acc,  off);
        sq_acc += __shfl_xor(sq_acc, off);
    }
    if (lane == 0)
        partial[(blockIdx.x << 2) | wave] =
            DT_F * d_acc - (0.5f * GAMMA_F * DT_F) * sq_acc;
}

// Finalize: thread b sums its 128 contiguous partials (32 KB total,
// L2-resident) and adds DT * sum_t bt[t] (b-independent, hoisted here
// so the hot kernel never touches bt).
__global__ void wealth_finalize_kernel(const float* __restrict__ partial,
                                       const float* __restrict__ bt,
                                       float* __restrict__ out) {
    const int b = threadIdx.x;  // 64 threads
    float bts = 0.f;
    const float4* bt4 = (const float4*)bt;
#pragma unroll
    for (int i = 0; i < T / 4; ++i) {
        float4 v = bt4[i];
        bts += (v.x + v.y) + (v.z + v.w);
    }
    const float4* p4 = (const float4*)(partial + b * (T / 4));
    float s = 0.f;
#pragma unroll
    for (int i = 0; i < T / 16; ++i) {
        float4 v = p4[i];
        s += (v.x + v.y) + (v.z + v.w);
    }
    out[b] = s + DT_F * bts;
}

extern "C" void kernel_launch(void* const* d_in, const int* in_sizes, int n_in,
                              void* d_out, int out_size, void* d_ws, size_t ws_size,
                              hipStream_t stream) {
    const float* action = (const float*)d_in[0];
    const float* mu     = (const float*)d_in[1];
    const float* sigma  = (const float*)d_in[2];
    const float* zeta   = (const float*)d_in[3];
    const float* bt     = (const float*)d_in[4];
    float* out = (float*)d_out;
    float* partial = (float*)d_ws;   // B*T/4 = 8192 floats = 32 KB

    wealth_partial_kernel<<<(B * T) / 16, 256, 0, stream>>>(
        action, mu, sigma, zeta, partial);
    wealth_finalize_kernel<<<1, B, 0, stream>>>(partial, bt, out);
}